// Round 28
// baseline (50.155 us; speedup 1.0000x reference)
//
#include <hip/hip_runtime.h>
#include <math.h>

#define D_DIM   128
#define MAXNORM 0.99f
#define MN2     (0.99f * 0.99f)

typedef float f32x4 __attribute__((ext_vector_type(4)));

// DPP-based reductions: VALU pipe only (r18-verified). Used ONLY in Mobius
// phases (unroll-1); hot matvec loops are accumulator-form (no reductions).
template <int CTRL, int MASK>
__device__ __forceinline__ float dpp_add(float x) {
  int y = __builtin_amdgcn_update_dpp(0, __float_as_int(x), CTRL, MASK, 0xf, true);
  return x + __int_as_float(y);
}
__device__ __forceinline__ float dpp_sum64(float x) {
  x = dpp_add<0x111, 0xf>(x);
  x = dpp_add<0x112, 0xf>(x);
  x = dpp_add<0x114, 0xf>(x);
  x = dpp_add<0x118, 0xf>(x);
  x = dpp_add<0x142, 0xa>(x);
  x = dpp_add<0x143, 0xc>(x);
  return __int_as_float(__builtin_amdgcn_readlane(__float_as_int(x), 63));
}
__device__ __forceinline__ float dpp_sum32(float x) {
  x = dpp_add<0x111, 0xf>(x);
  x = dpp_add<0x112, 0xf>(x);
  x = dpp_add<0x114, 0xf>(x);
  x = dpp_add<0x118, 0xf>(x);
  x = dpp_add<0x142, 0xa>(x);
  return x;
}

// ---- one-time transpose: rtt[c][j][i] = rot[c][i][j]. 64 charts x 16 tiles.
__global__ __launch_bounds__(256) void k_tr(
    const float* __restrict__ rot, float* __restrict__ rtt)
{
  __shared__ float tile[32][33];
  const int c = blockIdx.x >> 4;
  const int t = blockIdx.x & 15;
  const int ti = (t >> 2) * 32, tj = (t & 3) * 32;
  const int r = threadIdx.x >> 5, col = threadIdx.x & 31;
  const float* R = rot + ((size_t)c << 14);
  float* T = rtt + ((size_t)c << 14);
#pragma unroll
  for (int rr = 0; rr < 32; rr += 8)
    tile[r + rr][col] = R[(size_t)(ti + r + rr) * D_DIM + tj + col];
  __syncthreads();
#pragma unroll
  for (int rr = 0; rr < 32; rr += 8)
    T[(size_t)(tj + r + rr) * D_DIM + ti + col] = tile[col][r + rr];
}

// ---- main: one sample per 128-thread block; BOTH matvecs accumulator-form
// (stage A reads RtT rows), unroll 16, no DPP in hot loops -> no spill at the
// 64-VGPR cap (r25/r26 evidence: acc-form fits, dot-form w/ DPP chains spills).
__global__ __launch_bounds__(128, 8) void k_main(
    const float* __restrict__ z_n, const float* __restrict__ centers,
    const float* __restrict__ rtt, const float* __restrict__ rot,
    const int* __restrict__ src_idx, const int* __restrict__ tgt_idx,
    float* __restrict__ out, int B)
{
  __shared__ float zbuf[D_DIM];      // z_global
  __shared__ float pA[2][D_DIM];     // stage-A partials per wave (j-range split)
  __shared__ float pB[2][D_DIM];     // stage-B partials per wave

  const int tid = threadIdx.x;
  const int p = tid >> 6, l = tid & 63;
  const int h = l >> 5, q = l & 31;
  const int b = blockIdx.x;
  if (b >= B) return;

  const int ct = tgt_idx[b];
  const int cs = src_idx[b];

  // ---- Mobius A (replicated; p==0 publishes). Lane owns comps 2l,2l+1.
  float2 z = ((const float2*)(z_n + (size_t)b * D_DIM))[l];
  float2 c = ((const float2*)(centers + (size_t)cs * D_DIM))[l];
  {
    float y2p = dpp_sum64(z.x * z.x + z.y * z.y);
    float x2p = dpp_sum64(c.x * c.x + c.y * c.y);
    float cz  = dpp_sum64(c.x * z.x + c.y * z.y);
    float sz = 1.0f, y2 = y2p;
    if (y2p > MN2) { sz = MAXNORM / sqrtf(y2p); y2 = MN2; }
    float sc = 1.0f, x2 = x2p;
    if (x2p > MN2) { sc = MAXNORM / sqrtf(x2p); x2 = MN2; }
    float xy  = -(sc * sz) * cz;        // x = -c_source
    float nx  = 1.0f + 2.0f * xy + y2;
    float ny  = 1.0f - x2;
    float inv = 1.0f / fmaxf(1.0f + 2.0f * xy + x2 * y2, 1e-15f);
    float2 zg;
    zg.x = (nx * (-sc * c.x) + ny * (sz * z.x)) * inv;
    zg.y = (nx * (-sc * c.y) + ny * (sz * z.y)) * inv;
    if (p == 0) ((float2*)zbuf)[l] = zg;
  }
  __syncthreads();

  // ---- Stage A (acc-form): v_i = sum_j RtT[j][i] * zg[j].
  // Wave p owns j in [64p,64p+64), 2 rows/iter (1KB coalesced); lane accs
  // i = 4q..4q+3; halves (h) combine via one shfl_xor(32).
  {
    const float* Rt = rtt + ((size_t)ct << 14);
    f32x4 acc = {0.0f, 0.0f, 0.0f, 0.0f};
#pragma unroll 16
    for (int t = 0; t < 32; ++t) {
      const int j = 64 * p + 2 * t + h;
      f32x4 rr = *(const f32x4*)&Rt[(size_t)j * D_DIM + 4 * q];
      float zj = zbuf[j];               // 2 distinct addrs/wave -> broadcast
      acc[0] = fmaf(rr[0], zj, acc[0]);
      acc[1] = fmaf(rr[1], zj, acc[1]);
      acc[2] = fmaf(rr[2], zj, acc[2]);
      acc[3] = fmaf(rr[3], zj, acc[3]);
    }
#pragma unroll
    for (int m = 0; m < 4; ++m) acc[m] += __shfl_xor(acc[m], 32, 64);
    if (h == 0) *(f32x4*)&pA[p][4 * q] = acc;
  }
  __syncthreads();

  // ---- Stage B (acc-form): w_i = sum_j Rs[j][i] * v_j, v_j = pA[0][j]+pA[1][j].
  {
    const float* Rs = rot + ((size_t)cs << 14);
    f32x4 acc = {0.0f, 0.0f, 0.0f, 0.0f};
#pragma unroll 16
    for (int t = 0; t < 32; ++t) {
      const int j = 64 * p + 2 * t + h;
      f32x4 rr = *(const f32x4*)&Rs[(size_t)j * D_DIM + 4 * q];
      float vj = pA[0][j] + pA[1][j];   // broadcast reads
      acc[0] = fmaf(rr[0], vj, acc[0]);
      acc[1] = fmaf(rr[1], vj, acc[1]);
      acc[2] = fmaf(rr[2], vj, acc[2]);
      acc[3] = fmaf(rr[3], vj, acc[3]);
    }
#pragma unroll
    for (int m = 0; m < 4; ++m) acc[m] += __shfl_xor(acc[m], 32, 64);
    if (h == 0) *(f32x4*)&pB[p][4 * q] = acc;
  }
  __syncthreads();

  // ---- Mobius B + final projection (replicated; p==0 stores).
  {
    float2 w0 = ((const float2*)pB[0])[l];
    float2 w1 = ((const float2*)pB[1])[l];
    float2 wv; wv.x = w0.x + w1.x; wv.y = w0.y + w1.y;
    float2 t = ((const float2*)(centers + (size_t)ct * D_DIM))[l];

    float t2p = dpp_sum64(t.x * t.x + t.y * t.y);
    float w2  = dpp_sum64(wv.x * wv.x + wv.y * wv.y);
    float tw  = dpp_sum64(t.x * wv.x + t.y * wv.y);
    float st = 1.0f, x2 = t2p;
    if (t2p > MN2) { st = MAXNORM / sqrtf(t2p); x2 = MN2; }
    float xy  = st * tw;                // x = +c_target
    float nx  = 1.0f + 2.0f * xy + w2;
    float ny  = 1.0f - x2;
    float inv = 1.0f / fmaxf(1.0f + 2.0f * xy + x2 * w2, 1e-15f);
    float o0 = (nx * (st * t.x) + ny * wv.x) * inv;
    float o1 = (nx * (st * t.y) + ny * wv.y) * inv;

    float no2 = dpp_sum64(o0 * o0 + o1 * o1);
    if (no2 > MN2) { float sc = MAXNORM / sqrtf(no2); o0 *= sc; o1 *= sc; }

    if (p == 0) {
      float2 o; o.x = o0; o.y = o1;
      ((float2*)(out + (size_t)b * D_DIM))[l] = o;
    }
  }
}

// ---- fallback (ws too small): r27 kernel verbatim (29.8us verified).
__global__ __launch_bounds__(128, 8) void k_fb(
    const float* __restrict__ z_n, const float* __restrict__ centers,
    const float* __restrict__ rot, const int* __restrict__ src_idx,
    const int* __restrict__ tgt_idx, float* __restrict__ out, int B)
{
  __shared__ float zbuf[D_DIM];
  __shared__ float vbuf[D_DIM];
  __shared__ float pbuf[2][D_DIM];

  const int tid = threadIdx.x;
  const int p = tid >> 6, l = tid & 63;
  const int h = l >> 5, q = l & 31;
  const int b = blockIdx.x;
  if (b >= B) return;

  const int ct = tgt_idx[b];
  const int cs = src_idx[b];

  float2 z = ((const float2*)(z_n + (size_t)b * D_DIM))[l];
  float2 c = ((const float2*)(centers + (size_t)cs * D_DIM))[l];
  {
    float y2p = dpp_sum64(z.x * z.x + z.y * z.y);
    float x2p = dpp_sum64(c.x * c.x + c.y * c.y);
    float cz  = dpp_sum64(c.x * z.x + c.y * z.y);
    float sz = 1.0f, y2 = y2p;
    if (y2p > MN2) { sz = MAXNORM / sqrtf(y2p); y2 = MN2; }
    float sc = 1.0f, x2 = x2p;
    if (x2p > MN2) { sc = MAXNORM / sqrtf(x2p); x2 = MN2; }
    float xy  = -(sc * sz) * cz;
    float nx  = 1.0f + 2.0f * xy + y2;
    float ny  = 1.0f - x2;
    float inv = 1.0f / fmaxf(1.0f + 2.0f * xy + x2 * y2, 1e-15f);
    float2 zg;
    zg.x = (nx * (-sc * c.x) + ny * (sz * z.x)) * inv;
    zg.y = (nx * (-sc * c.y) + ny * (sz * z.y)) * inv;
    if (p == 0) ((float2*)zbuf)[l] = zg;
  }
  __syncthreads();

  {
    const float* Rt = rot + ((size_t)ct << 14);
    const f32x4 zc = *(const f32x4*)&zbuf[4 * q];
#pragma unroll 8
    for (int t = 0; t < 32; ++t) {
      const int r = 64 * p + 2 * t + h;
      f32x4 rr = *(const f32x4*)&Rt[(size_t)r * D_DIM + 4 * q];
      float pv = fmaf(rr[3], zc[3], fmaf(rr[2], zc[2], fmaf(rr[1], zc[1], rr[0] * zc[0])));
      pv = dpp_sum32(pv);
      if (q == 31) vbuf[r] = pv;
    }
  }
  __syncthreads();

  {
    const float* Rs = rot + ((size_t)cs << 14);
    f32x4 acc = {0.0f, 0.0f, 0.0f, 0.0f};
#pragma unroll 16
    for (int t = 0; t < 32; ++t) {
      const int j = 64 * p + 2 * t + h;
      f32x4 rr = *(const f32x4*)&Rs[(size_t)j * D_DIM + 4 * q];
      float vj = vbuf[j];
      acc[0] = fmaf(rr[0], vj, acc[0]);
      acc[1] = fmaf(rr[1], vj, acc[1]);
      acc[2] = fmaf(rr[2], vj, acc[2]);
      acc[3] = fmaf(rr[3], vj, acc[3]);
    }
#pragma unroll
    for (int m = 0; m < 4; ++m) acc[m] += __shfl_xor(acc[m], 32, 64);
    if (h == 0) *(f32x4*)&pbuf[p][4 * q] = acc;
  }
  __syncthreads();

  {
    float2 w0 = ((const float2*)pbuf[0])[l];
    float2 w1 = ((const float2*)pbuf[1])[l];
    float2 wv; wv.x = w0.x + w1.x; wv.y = w0.y + w1.y;
    float2 t = ((const float2*)(centers + (size_t)ct * D_DIM))[l];

    float t2p = dpp_sum64(t.x * t.x + t.y * t.y);
    float w2  = dpp_sum64(wv.x * wv.x + wv.y * wv.y);
    float tw  = dpp_sum64(t.x * wv.x + t.y * wv.y);
    float st = 1.0f, x2 = t2p;
    if (t2p > MN2) { st = MAXNORM / sqrtf(t2p); x2 = MN2; }
    float xy  = st * tw;
    float nx  = 1.0f + 2.0f * xy + w2;
    float ny  = 1.0f - x2;
    float inv = 1.0f / fmaxf(1.0f + 2.0f * xy + x2 * w2, 1e-15f);
    float o0 = (nx * (st * t.x) + ny * wv.x) * inv;
    float o1 = (nx * (st * t.y) + ny * wv.y) * inv;

    float no2 = dpp_sum64(o0 * o0 + o1 * o1);
    if (no2 > MN2) { float sc = MAXNORM / sqrtf(no2); o0 *= sc; o1 *= sc; }

    if (p == 0) {
      float2 o; o.x = o0; o.y = o1;
      ((float2*)(out + (size_t)b * D_DIM))[l] = o;
    }
  }
}

extern "C" void kernel_launch(void* const* d_in, const int* in_sizes, int n_in,
                              void* d_out, int out_size, void* d_ws, size_t ws_size,
                              hipStream_t stream) {
  const float* z_n     = (const float*)d_in[0];
  const float* centers = (const float*)d_in[1];
  const float* rot     = (const float*)d_in[2];
  const int*   src     = (const int*)d_in[3];
  const int*   tgt     = (const int*)d_in[4];
  float* out = (float*)d_out;
  const int B = in_sizes[3];
  const size_t need = (size_t)64 * D_DIM * D_DIM * sizeof(float);   // 4 MiB

  if (ws_size >= need) {
    float* rtt = (float*)d_ws;
    k_tr<<<dim3(64 * 16), dim3(256), 0, stream>>>(rot, rtt);
    k_main<<<dim3(B), dim3(128), 0, stream>>>(z_n, centers, rtt, rot, src, tgt, out, B);
  } else {
    k_fb<<<dim3(B), dim3(128), 0, stream>>>(z_n, centers, rot, src, tgt, out, B);
  }
}

// Round 29
// 32.909 us; speedup vs baseline: 1.5240x; 1.5240x over previous
//
#include <hip/hip_runtime.h>
#include <math.h>

#define D_DIM   128
#define MAXNORM 0.99f
#define MN2     (0.99f * 0.99f)

typedef float f32x4 __attribute__((ext_vector_type(4)));

// DPP-based reductions: VALU pipe only (r18-verified).
template <int CTRL, int MASK>
__device__ __forceinline__ float dpp_add(float x) {
  int y = __builtin_amdgcn_update_dpp(0, __float_as_int(x), CTRL, MASK, 0xf, true);
  return x + __int_as_float(y);
}
__device__ __forceinline__ float dpp_sum64(float x) {
  x = dpp_add<0x111, 0xf>(x);
  x = dpp_add<0x112, 0xf>(x);
  x = dpp_add<0x114, 0xf>(x);
  x = dpp_add<0x118, 0xf>(x);
  x = dpp_add<0x142, 0xa>(x);
  x = dpp_add<0x143, 0xc>(x);
  return __int_as_float(__builtin_amdgcn_readlane(__float_as_int(x), 63));
}
__device__ __forceinline__ float dpp_sum32(float x) {
  x = dpp_add<0x111, 0xf>(x);
  x = dpp_add<0x112, 0xf>(x);
  x = dpp_add<0x114, 0xf>(x);
  x = dpp_add<0x118, 0xf>(x);
  x = dpp_add<0x142, 0xa>(x);
  return x;
}

// bf16 helpers: RNE float->bf16, cheap bf16->float.
__device__ __forceinline__ unsigned short f2bf(float f) {
  unsigned u = __float_as_uint(f);
  return (unsigned short)((u + 0x7FFFu + ((u >> 16) & 1u)) >> 16);
}
__device__ __forceinline__ float bf2f(unsigned short s) {
  return __uint_as_float(((unsigned)s) << 16);
}

// ---- cast rotations to bf16 once per call: 1M elems, 4/thread, 1024 blocks.
__global__ __launch_bounds__(256) void k_cast(
    const float* __restrict__ rot, unsigned short* __restrict__ rb)
{
  const int i = blockIdx.x * 256 + threadIdx.x;
  f32x4 v = ((const f32x4*)rot)[i];
  ushort4 o;
  o.x = f2bf(v[0]); o.y = f2bf(v[1]); o.z = f2bf(v[2]); o.w = f2bf(v[3]);
  ((ushort4*)rb)[i] = o;
}

// ---- main: r27 structure verbatim (one sample / 128-thread block, A=8 dot,
// B=16 acc), ONLY the matrix loads changed f32x4 -> ushort4 (bf16).
// Halves matrix traffic 512->256MB AND halves in-flight load registers.
__global__ __launch_bounds__(128, 8) void k_main(
    const float* __restrict__ z_n, const float* __restrict__ centers,
    const unsigned short* __restrict__ rb, const int* __restrict__ src_idx,
    const int* __restrict__ tgt_idx, float* __restrict__ out, int B)
{
  __shared__ float zbuf[D_DIM];
  __shared__ float vbuf[D_DIM];
  __shared__ float pbuf[2][D_DIM];

  const int tid = threadIdx.x;
  const int p = tid >> 6, l = tid & 63;
  const int h = l >> 5, q = l & 31;
  const int b = blockIdx.x;
  if (b >= B) return;

  const int ct = tgt_idx[b];
  const int cs = src_idx[b];

  // ---- Mobius A (replicated in pair; p==0 publishes). Lane owns comps 2l,2l+1.
  float2 z = ((const float2*)(z_n + (size_t)b * D_DIM))[l];
  float2 c = ((const float2*)(centers + (size_t)cs * D_DIM))[l];
  {
    float y2p = dpp_sum64(z.x * z.x + z.y * z.y);
    float x2p = dpp_sum64(c.x * c.x + c.y * c.y);
    float cz  = dpp_sum64(c.x * z.x + c.y * z.y);
    float sz = 1.0f, y2 = y2p;
    if (y2p > MN2) { sz = MAXNORM / sqrtf(y2p); y2 = MN2; }
    float sc = 1.0f, x2 = x2p;
    if (x2p > MN2) { sc = MAXNORM / sqrtf(x2p); x2 = MN2; }
    float xy  = -(sc * sz) * cz;        // x = -c_source
    float nx  = 1.0f + 2.0f * xy + y2;
    float ny  = 1.0f - x2;
    float inv = 1.0f / fmaxf(1.0f + 2.0f * xy + x2 * y2, 1e-15f);
    float2 zg;
    zg.x = (nx * (-sc * c.x) + ny * (sz * z.x)) * inv;
    zg.y = (nx * (-sc * c.y) + ny * (sz * z.y)) * inv;
    if (p == 0) ((float2*)zbuf)[l] = zg;
  }
  __syncthreads();

  // ---- Stage A (dot-form, unroll 8): v = Rt @ zg. Wave p rows [64p,64p+64).
  // ushort4 load = 8B/lane, 512B/wave-instr contiguous (coalesced).
  {
    const unsigned short* Rt = rb + ((size_t)ct << 14);
    const f32x4 zc = *(const f32x4*)&zbuf[4 * q];
#pragma unroll 8
    for (int t = 0; t < 32; ++t) {
      const int r = 64 * p + 2 * t + h;
      ushort4 rr = *(const ushort4*)&Rt[(size_t)r * D_DIM + 4 * q];
      float pv = fmaf(bf2f(rr.w), zc[3],
                 fmaf(bf2f(rr.z), zc[2],
                 fmaf(bf2f(rr.y), zc[1], bf2f(rr.x) * zc[0])));
      pv = dpp_sum32(pv);
      if (q == 31) vbuf[r] = pv;
    }
  }
  __syncthreads();

  // ---- Stage B (acc-form, unroll 16): w_i = sum_j Rs[j][i] v_j.
  {
    const unsigned short* Rs = rb + ((size_t)cs << 14);
    f32x4 acc = {0.0f, 0.0f, 0.0f, 0.0f};
#pragma unroll 16
    for (int t = 0; t < 32; ++t) {
      const int j = 64 * p + 2 * t + h;
      ushort4 rr = *(const ushort4*)&Rs[(size_t)j * D_DIM + 4 * q];
      float vj = vbuf[j];
      acc[0] = fmaf(bf2f(rr.x), vj, acc[0]);
      acc[1] = fmaf(bf2f(rr.y), vj, acc[1]);
      acc[2] = fmaf(bf2f(rr.z), vj, acc[2]);
      acc[3] = fmaf(bf2f(rr.w), vj, acc[3]);
    }
#pragma unroll
    for (int m = 0; m < 4; ++m) acc[m] += __shfl_xor(acc[m], 32, 64);
    if (h == 0) *(f32x4*)&pbuf[p][4 * q] = acc;
  }
  __syncthreads();

  // ---- Mobius B + final projection (replicated; p==0 stores).
  {
    float2 w0 = ((const float2*)pbuf[0])[l];
    float2 w1 = ((const float2*)pbuf[1])[l];
    float2 wv; wv.x = w0.x + w1.x; wv.y = w0.y + w1.y;
    float2 t = ((const float2*)(centers + (size_t)ct * D_DIM))[l];

    float t2p = dpp_sum64(t.x * t.x + t.y * t.y);
    float w2  = dpp_sum64(wv.x * wv.x + wv.y * wv.y);
    float tw  = dpp_sum64(t.x * wv.x + t.y * wv.y);
    float st = 1.0f, x2 = t2p;
    if (t2p > MN2) { st = MAXNORM / sqrtf(t2p); x2 = MN2; }
    float xy  = st * tw;                // x = +c_target
    float nx  = 1.0f + 2.0f * xy + w2;
    float ny  = 1.0f - x2;
    float inv = 1.0f / fmaxf(1.0f + 2.0f * xy + x2 * w2, 1e-15f);
    float o0 = (nx * (st * t.x) + ny * wv.x) * inv;
    float o1 = (nx * (st * t.y) + ny * wv.y) * inv;

    float no2 = dpp_sum64(o0 * o0 + o1 * o1);
    if (no2 > MN2) { float sc = MAXNORM / sqrtf(no2); o0 *= sc; o1 *= sc; }

    if (p == 0) {
      float2 o; o.x = o0; o.y = o1;
      ((float2*)(out + (size_t)b * D_DIM))[l] = o;
    }
  }
}

// ---- fallback (ws too small): r27 kernel verbatim (29.8us verified, f32).
__global__ __launch_bounds__(128, 8) void k_fb(
    const float* __restrict__ z_n, const float* __restrict__ centers,
    const float* __restrict__ rot, const int* __restrict__ src_idx,
    const int* __restrict__ tgt_idx, float* __restrict__ out, int B)
{
  __shared__ float zbuf[D_DIM];
  __shared__ float vbuf[D_DIM];
  __shared__ float pbuf[2][D_DIM];

  const int tid = threadIdx.x;
  const int p = tid >> 6, l = tid & 63;
  const int h = l >> 5, q = l & 31;
  const int b = blockIdx.x;
  if (b >= B) return;

  const int ct = tgt_idx[b];
  const int cs = src_idx[b];

  float2 z = ((const float2*)(z_n + (size_t)b * D_DIM))[l];
  float2 c = ((const float2*)(centers + (size_t)cs * D_DIM))[l];
  {
    float y2p = dpp_sum64(z.x * z.x + z.y * z.y);
    float x2p = dpp_sum64(c.x * c.x + c.y * c.y);
    float cz  = dpp_sum64(c.x * z.x + c.y * z.y);
    float sz = 1.0f, y2 = y2p;
    if (y2p > MN2) { sz = MAXNORM / sqrtf(y2p); y2 = MN2; }
    float sc = 1.0f, x2 = x2p;
    if (x2p > MN2) { sc = MAXNORM / sqrtf(x2p); x2 = MN2; }
    float xy  = -(sc * sz) * cz;
    float nx  = 1.0f + 2.0f * xy + y2;
    float ny  = 1.0f - x2;
    float inv = 1.0f / fmaxf(1.0f + 2.0f * xy + x2 * y2, 1e-15f);
    float2 zg;
    zg.x = (nx * (-sc * c.x) + ny * (sz * z.x)) * inv;
    zg.y = (nx * (-sc * c.y) + ny * (sz * z.y)) * inv;
    if (p == 0) ((float2*)zbuf)[l] = zg;
  }
  __syncthreads();

  {
    const float* Rt = rot + ((size_t)ct << 14);
    const f32x4 zc = *(const f32x4*)&zbuf[4 * q];
#pragma unroll 8
    for (int t = 0; t < 32; ++t) {
      const int r = 64 * p + 2 * t + h;
      f32x4 rr = *(const f32x4*)&Rt[(size_t)r * D_DIM + 4 * q];
      float pv = fmaf(rr[3], zc[3], fmaf(rr[2], zc[2], fmaf(rr[1], zc[1], rr[0] * zc[0])));
      pv = dpp_sum32(pv);
      if (q == 31) vbuf[r] = pv;
    }
  }
  __syncthreads();

  {
    const float* Rs = rot + ((size_t)cs << 14);
    f32x4 acc = {0.0f, 0.0f, 0.0f, 0.0f};
#pragma unroll 16
    for (int t = 0; t < 32; ++t) {
      const int j = 64 * p + 2 * t + h;
      f32x4 rr = *(const f32x4*)&Rs[(size_t)j * D_DIM + 4 * q];
      float vj = vbuf[j];
      acc[0] = fmaf(rr[0], vj, acc[0]);
      acc[1] = fmaf(rr[1], vj, acc[1]);
      acc[2] = fmaf(rr[2], vj, acc[2]);
      acc[3] = fmaf(rr[3], vj, acc[3]);
    }
#pragma unroll
    for (int m = 0; m < 4; ++m) acc[m] += __shfl_xor(acc[m], 32, 64);
    if (h == 0) *(f32x4*)&pbuf[p][4 * q] = acc;
  }
  __syncthreads();

  {
    float2 w0 = ((const float2*)pbuf[0])[l];
    float2 w1 = ((const float2*)pbuf[1])[l];
    float2 wv; wv.x = w0.x + w1.x; wv.y = w0.y + w1.y;
    float2 t = ((const float2*)(centers + (size_t)ct * D_DIM))[l];

    float t2p = dpp_sum64(t.x * t.x + t.y * t.y);
    float w2  = dpp_sum64(wv.x * wv.x + wv.y * wv.y);
    float tw  = dpp_sum64(t.x * wv.x + t.y * wv.y);
    float st = 1.0f, x2 = t2p;
    if (t2p > MN2) { st = MAXNORM / sqrtf(t2p); x2 = MN2; }
    float xy  = st * tw;
    float nx  = 1.0f + 2.0f * xy + w2;
    float ny  = 1.0f - x2;
    float inv = 1.0f / fmaxf(1.0f + 2.0f * xy + x2 * w2, 1e-15f);
    float o0 = (nx * (st * t.x) + ny * wv.x) * inv;
    float o1 = (nx * (st * t.y) + ny * wv.y) * inv;

    float no2 = dpp_sum64(o0 * o0 + o1 * o1);
    if (no2 > MN2) { float sc = MAXNORM / sqrtf(no2); o0 *= sc; o1 *= sc; }

    if (p == 0) {
      float2 o; o.x = o0; o.y = o1;
      ((float2*)(out + (size_t)b * D_DIM))[l] = o;
    }
  }
}

extern "C" void kernel_launch(void* const* d_in, const int* in_sizes, int n_in,
                              void* d_out, int out_size, void* d_ws, size_t ws_size,
                              hipStream_t stream) {
  const float* z_n     = (const float*)d_in[0];
  const float* centers = (const float*)d_in[1];
  const float* rot     = (const float*)d_in[2];
  const int*   src     = (const int*)d_in[3];
  const int*   tgt     = (const int*)d_in[4];
  float* out = (float*)d_out;
  const int B = in_sizes[3];
  const size_t need = (size_t)64 * D_DIM * D_DIM * sizeof(unsigned short);  // 2 MiB

  if (ws_size >= need) {
    unsigned short* rb = (unsigned short*)d_ws;
    k_cast<<<dim3(1024), dim3(256), 0, stream>>>(rot, rb);
    k_main<<<dim3(B), dim3(128), 0, stream>>>(z_n, centers, rb, src, tgt, out, B);
  } else {
    k_fb<<<dim3(B), dim3(128), 0, stream>>>(z_n, centers, rot, src, tgt, out, B);
  }
}

// Round 30
// 29.582 us; speedup vs baseline: 1.6954x; 1.1125x over previous
//
#include <hip/hip_runtime.h>
#include <math.h>

#define D_DIM   128
#define MAXNORM 0.99f
#define MN2     (0.99f * 0.99f)

typedef float f32x4 __attribute__((ext_vector_type(4)));

// DPP-based reductions: VALU pipe only (r18-verified).
template <int CTRL, int MASK>
__device__ __forceinline__ float dpp_add(float x) {
  int y = __builtin_amdgcn_update_dpp(0, __float_as_int(x), CTRL, MASK, 0xf, true);
  return x + __int_as_float(y);
}
__device__ __forceinline__ float dpp_sum64(float x) {
  x = dpp_add<0x111, 0xf>(x);   // row_shr:1
  x = dpp_add<0x112, 0xf>(x);   // row_shr:2
  x = dpp_add<0x114, 0xf>(x);   // row_shr:4
  x = dpp_add<0x118, 0xf>(x);   // row_shr:8
  x = dpp_add<0x142, 0xa>(x);   // row_bcast15
  x = dpp_add<0x143, 0xc>(x);   // row_bcast31
  return __int_as_float(__builtin_amdgcn_readlane(__float_as_int(x), 63));
}
__device__ __forceinline__ float dpp_sum32(float x) {
  x = dpp_add<0x111, 0xf>(x);
  x = dpp_add<0x112, 0xf>(x);
  x = dpp_add<0x114, 0xf>(x);
  x = dpp_add<0x118, 0xf>(x);
  x = dpp_add<0x142, 0xa>(x);
  return x;
}

// r25 FINAL (29.5us verified): 2 samples per 256-thread block, 2 waves/sample.
// Ledger of falsified alternatives: stage-A unroll16 spills (r26: 48MB scratch);
// transpose thrashes L2 (r28: 8MB footprint, FETCH 80MB); bf16 adds VALU+cast
// (r29: +3.4us); LDS chart-staging loses occupancy (r19); NS-batch reuse
// doesn't help because the structure is latency- not BW-bound (r24).
// launch_bounds(256,8): 8 waves/SIMD -> VGPR cap 64.
__global__ __launch_bounds__(256, 8) void k_all(
    const float* __restrict__ z_n, const float* __restrict__ centers,
    const float* __restrict__ rot, const int* __restrict__ src_idx,
    const int* __restrict__ tgt_idx, float* __restrict__ out, int B)
{
  __shared__ float zbuf[2][D_DIM];      // z_global per sample slot
  __shared__ float vbuf[2][D_DIM];      // v = Rt @ zg
  __shared__ float pbuf[2][2][D_DIM];   // stage-B partials [p][s][i]

  const int tid = threadIdx.x;
  const int w = tid >> 6, l = tid & 63;
  const int s = w >> 1, p = w & 1;      // sample slot, wave-within-pair
  const int h = l >> 5, q = l & 31;
  int b = blockIdx.x * 2 + s;
  if (b >= B) b = B - 1;                // tail duplicates write identical values

  const int ct = tgt_idx[b];
  const int cs = src_idx[b];

  // ---- Mobius A (replicated in the pair; p==0 publishes). Lane owns comps 2l,2l+1.
  float2 z = ((const float2*)(z_n + (size_t)b * D_DIM))[l];
  float2 c = ((const float2*)(centers + (size_t)cs * D_DIM))[l];
  {
    float y2p = dpp_sum64(z.x * z.x + z.y * z.y);
    float x2p = dpp_sum64(c.x * c.x + c.y * c.y);
    float cz  = dpp_sum64(c.x * z.x + c.y * z.y);
    float sz = 1.0f, y2 = y2p;
    if (y2p > MN2) { sz = MAXNORM / sqrtf(y2p); y2 = MN2; }
    float sc = 1.0f, x2 = x2p;
    if (x2p > MN2) { sc = MAXNORM / sqrtf(x2p); x2 = MN2; }
    float xy  = -(sc * sz) * cz;        // x = -c_source
    float nx  = 1.0f + 2.0f * xy + y2;
    float ny  = 1.0f - x2;
    float inv = 1.0f / fmaxf(1.0f + 2.0f * xy + x2 * y2, 1e-15f);
    float2 zg;
    zg.x = (nx * (-sc * c.x) + ny * (sz * z.x)) * inv;
    zg.y = (nx * (-sc * c.y) + ny * (sz * z.y)) * inv;
    if (p == 0) ((float2*)zbuf[s])[l] = zg;
  }
  __syncthreads();

  // ---- Stage A: v = Rt @ zg. Wave p owns rows [64p,64p+64), 2 rows/iter.
  // unroll 8: 16 spills under the 64-VGPR cap (r26 evidence).
  {
    const float* Rt = rot + (size_t)ct * D_DIM * D_DIM;
    const f32x4 zc = *(const f32x4*)&zbuf[s][4 * q];
#pragma unroll 8
    for (int t = 0; t < 32; ++t) {
      const int r = 64 * p + 2 * t + h;
      f32x4 rr = *(const f32x4*)&Rt[(size_t)r * D_DIM + 4 * q];
      float pv = fmaf(rr[3], zc[3], fmaf(rr[2], zc[2], fmaf(rr[1], zc[1], rr[0] * zc[0])));
      pv = dpp_sum32(pv);
      if (q == 31) vbuf[s][r] = pv;
    }
  }
  __syncthreads();

  // ---- Stage B: w_i = sum_j Rs[j][i] v_j. Wave p owns j in [64p,64p+64).
  // unroll 16 (r25-verified win: latency-starved at 8, acc-form fits VGPR cap).
  {
    const float* Rs = rot + (size_t)cs * D_DIM * D_DIM;
    f32x4 acc = {0.0f, 0.0f, 0.0f, 0.0f};
#pragma unroll 16
    for (int t = 0; t < 32; ++t) {
      const int j = 64 * p + 2 * t + h;
      f32x4 rr = *(const f32x4*)&Rs[(size_t)j * D_DIM + 4 * q];
      float vj = vbuf[s][j];
      acc[0] = fmaf(rr[0], vj, acc[0]);
      acc[1] = fmaf(rr[1], vj, acc[1]);
      acc[2] = fmaf(rr[2], vj, acc[2]);
      acc[3] = fmaf(rr[3], vj, acc[3]);
    }
#pragma unroll
    for (int m = 0; m < 4; ++m) acc[m] += __shfl_xor(acc[m], 32, 64);
    if (h == 0) *(f32x4*)&pbuf[p][s][4 * q] = acc;
  }
  __syncthreads();

  // ---- Mobius B + final projection (replicated in pair; p==0 stores).
  {
    float2 w0 = ((const float2*)pbuf[0][s])[l];
    float2 w1 = ((const float2*)pbuf[1][s])[l];
    float2 wv; wv.x = w0.x + w1.x; wv.y = w0.y + w1.y;
    float2 t = ((const float2*)(centers + (size_t)ct * D_DIM))[l];

    float t2p = dpp_sum64(t.x * t.x + t.y * t.y);
    float w2  = dpp_sum64(wv.x * wv.x + wv.y * wv.y);
    float tw  = dpp_sum64(t.x * wv.x + t.y * wv.y);
    float st = 1.0f, x2 = t2p;
    if (t2p > MN2) { st = MAXNORM / sqrtf(t2p); x2 = MN2; }
    float xy  = st * tw;                // x = +c_target
    float nx  = 1.0f + 2.0f * xy + w2;
    float ny  = 1.0f - x2;
    float inv = 1.0f / fmaxf(1.0f + 2.0f * xy + x2 * w2, 1e-15f);
    float o0 = (nx * (st * t.x) + ny * wv.x) * inv;
    float o1 = (nx * (st * t.y) + ny * wv.y) * inv;

    float no2 = dpp_sum64(o0 * o0 + o1 * o1);
    if (no2 > MN2) { float sc = MAXNORM / sqrtf(no2); o0 *= sc; o1 *= sc; }

    if (p == 0) {
      float2 o; o.x = o0; o.y = o1;
      ((float2*)(out + (size_t)b * D_DIM))[l] = o;
    }
  }
}

extern "C" void kernel_launch(void* const* d_in, const int* in_sizes, int n_in,
                              void* d_out, int out_size, void* d_ws, size_t ws_size,
                              hipStream_t stream) {
  const float* z_n     = (const float*)d_in[0];
  const float* centers = (const float*)d_in[1];
  const float* rot     = (const float*)d_in[2];
  const int*   src     = (const int*)d_in[3];
  const int*   tgt     = (const int*)d_in[4];
  float* out = (float*)d_out;
  const int B = in_sizes[3];

  const int blocks = (B + 1) / 2;       // 2 samples per block
  k_all<<<dim3(blocks), dim3(256), 0, stream>>>(z_n, centers, rot, src, tgt, out, B);
}